// Round 1
// baseline (506.160 us; speedup 1.0000x reference)
//
#include <hip/hip_runtime.h>

// GCLSTM (single step, H=C=0) + MLP head, fully fused, fp32.
// Dead inputs: edge_index, edge_weight, W_f, Uc_*, bc_f, w_ci, w_cf, b_f.
//
// Per node:
//   I = sigmoid(x@W_i + bc_i + b_i)
//   T = tanh   (x@W_c + bc_c + b_c)
//   C = I*T
//   O = sigmoid(x@W_o + bc_o + w_co*C + b_o)
//   H = relu(O * tanh(C))
//   out = relu(relu(H@M1+bm1)@M2+bm2)@M3 + bm3

constexpr int IN_F  = 16;
constexpr int HID   = 128;
constexpr int MH1   = 64;
constexpr int MH2   = 32;
constexpr int CHUNK = 16;   // hid elements per gate chunk (3*16 = 48 accumulators)

__device__ __forceinline__ float fast_sigmoid(float v) {
    return __builtin_amdgcn_rcpf(1.0f + __expf(-v));
}
__device__ __forceinline__ float fast_tanh(float v) {
    // stable for all v: exp(2v)->inf => 1, exp(2v)->0 => -1
    return 1.0f - 2.0f * __builtin_amdgcn_rcpf(1.0f + __expf(2.0f * v));
}

__global__ __launch_bounds__(256) void gclstm_fused_kernel(
    const float* __restrict__ x,
    const float* __restrict__ W_i, const float* __restrict__ W_c, const float* __restrict__ W_o,
    const float* __restrict__ bc_i, const float* __restrict__ bc_c, const float* __restrict__ bc_o,
    const float* __restrict__ w_co,
    const float* __restrict__ b_i, const float* __restrict__ b_c, const float* __restrict__ b_o,
    const float* __restrict__ M1, const float* __restrict__ bm1,
    const float* __restrict__ M2, const float* __restrict__ bm2,
    const float* __restrict__ M3, const float* __restrict__ bm3,
    float* __restrict__ out, int n)
{
    const int node = blockIdx.x * blockDim.x + threadIdx.x;
    if (node >= n) return;

    // ---- load x[16] (64B contiguous per thread) ----
    float xv[IN_F];
    {
        const float4* xp = reinterpret_cast<const float4*>(x + (size_t)node * IN_F);
        #pragma unroll
        for (int q = 0; q < IN_F / 4; ++q) {
            float4 v = xp[q];
            xv[4*q+0] = v.x; xv[4*q+1] = v.y; xv[4*q+2] = v.z; xv[4*q+3] = v.w;
        }
    }

    // ---- m1 accumulators (MLP layer 1), fed by streamed H ----
    float m1[MH1];
    #pragma unroll
    for (int k = 0; k < MH1; ++k) m1[k] = bm1[k];

    // ---- gates, processed CHUNK hid-elements at a time ----
    #pragma unroll 1
    for (int j0 = 0; j0 < HID; j0 += CHUNK) {
        float ai[CHUNK], ac[CHUNK], ao[CHUNK];
        #pragma unroll
        for (int j = 0; j < CHUNK; ++j) {
            ai[j] = bc_i[j0 + j] + b_i[j0 + j];
            ac[j] = bc_c[j0 + j] + b_c[j0 + j];
            ao[j] = bc_o[j0 + j] + b_o[j0 + j];
        }
        #pragma unroll
        for (int k = 0; k < IN_F; ++k) {
            const float xk = xv[k];
            const float* __restrict__ wi = W_i + k * HID + j0;
            const float* __restrict__ wc = W_c + k * HID + j0;
            const float* __restrict__ wo = W_o + k * HID + j0;
            #pragma unroll
            for (int j = 0; j < CHUNK; ++j) {
                ai[j] = fmaf(xk, wi[j], ai[j]);
                ac[j] = fmaf(xk, wc[j], ac[j]);
                ao[j] = fmaf(xk, wo[j], ao[j]);
            }
        }
        #pragma unroll
        for (int j = 0; j < CHUNK; ++j) {
            const float Ig = fast_sigmoid(ai[j]);
            const float Tg = fast_tanh(ac[j]);
            const float c  = Ig * Tg;
            const float Og = fast_sigmoid(fmaf(w_co[j0 + j], c, ao[j]));
            float h = Og * fast_tanh(c);
            h = fmaxf(h, 0.0f);                         // relu(H)
            const float* __restrict__ r = M1 + (size_t)(j0 + j) * MH1;
            #pragma unroll
            for (int k = 0; k < MH1; ++k) m1[k] = fmaf(h, r[k], m1[k]);
        }
    }

    // ---- MLP layer 2: 64 -> 32 ----
    float m2[MH2];
    #pragma unroll
    for (int k = 0; k < MH2; ++k) m2[k] = bm2[k];
    #pragma unroll 4
    for (int j = 0; j < MH1; ++j) {
        const float h = fmaxf(m1[j], 0.0f);
        const float* __restrict__ r = M2 + (size_t)j * MH2;
        #pragma unroll
        for (int k = 0; k < MH2; ++k) m2[k] = fmaf(h, r[k], m2[k]);
    }

    // ---- MLP layer 3: 32 -> 1 ----
    float acc = bm3[0];
    #pragma unroll
    for (int k = 0; k < MH2; ++k) acc = fmaf(fmaxf(m2[k], 0.0f), M3[k], acc);

    out[node] = acc;
}

extern "C" void kernel_launch(void* const* d_in, const int* in_sizes, int n_in,
                              void* d_out, int out_size, void* d_ws, size_t ws_size,
                              hipStream_t stream) {
    const float* x    = (const float*)d_in[0];
    // d_in[1] edge_index, d_in[2] edge_weight: dead (ChebConv K=1 on H=0)
    const float* W_i  = (const float*)d_in[3];
    // d_in[4] W_f: dead (multiplies C=0)
    const float* W_c  = (const float*)d_in[5];
    const float* W_o  = (const float*)d_in[6];
    // d_in[7..10] Uc_*: dead (H=0)
    const float* bc_i = (const float*)d_in[11];
    // d_in[12] bc_f: dead
    const float* bc_c = (const float*)d_in[13];
    const float* bc_o = (const float*)d_in[14];
    // d_in[15] w_ci, d_in[16] w_cf: dead (C_old=0)
    const float* w_co = (const float*)d_in[17];
    const float* b_i  = (const float*)d_in[18];
    // d_in[19] b_f: dead
    const float* b_c  = (const float*)d_in[20];
    const float* b_o  = (const float*)d_in[21];
    const float* M1   = (const float*)d_in[22];
    const float* bm1  = (const float*)d_in[23];
    const float* M2   = (const float*)d_in[24];
    const float* bm2  = (const float*)d_in[25];
    const float* M3   = (const float*)d_in[26];
    const float* bm3  = (const float*)d_in[27];
    float* out = (float*)d_out;

    const int n = in_sizes[0] / IN_F;   // 500000
    const int block = 256;
    const int grid = (n + block - 1) / block;

    gclstm_fused_kernel<<<grid, block, 0, stream>>>(
        x, W_i, W_c, W_o, bc_i, bc_c, bc_o, w_co,
        b_i, b_c, b_o, M1, bm1, M2, bm2, M3, bm3, out, n);
}

// Round 2
// 104.830 us; speedup vs baseline: 4.8284x; 4.8284x over previous
//
#include <hip/hip_runtime.h>
#include <stdint.h>

// GCLSTM (single step, H=C=0) + MLP head, bf16 MFMA, fp32 accum/activations.
// Everything computed TRANSPOSED: G^T[128x16] = W^T[128x16in] @ X^T[16inx16nodes]
// so C-fragments hold (col=node, row=feature) and the x B-frag is a plain
// coalesced load. H^T and m1^T round-trip through per-wave LDS buffers stored
// in frag-linear order (ds_read_b128 at lane*16, conflict-free).

typedef __attribute__((ext_vector_type(8))) short bf16x8;   // 8 bf16 = 4 VGPR
typedef __attribute__((ext_vector_type(4))) float f32x4;

constexpr int IN_F = 16;
constexpr int HID  = 128;
constexpr int MH1  = 64;
constexpr int MH2  = 32;
constexpr int ITER = 4;                     // row-tiles per wave per block
constexpr int TILES_PER_BLOCK = 4 * ITER;   // 4 waves

// ---- LDS byte offsets ----
constexpr int GATE_F = 0;                   // 24 tiles * 512 B (lanes 0..31 real)
constexpr int M1_F   = 12288;               // 16 tiles * 1024 B
constexpr int M2_F   = 28672;               // 4 tiles * 1024 B
constexpr int BIAS_O = 32768;               // 3*128 f32 (combined bc_*+b_*)
constexpr int WCO_O  = 34304;               // 128 f32
constexpr int M3_O   = 34816;               // 32 f32
constexpr int BM1_O  = 34944;               // 64 f32
constexpr int BM2_O  = 35200;               // 32 f32
constexpr int BM3_O  = 35328;               // 1 f32
constexpr int SCR_O  = 36864;               // per-wave: HT 4096 + M1T 2048
constexpr int LDS_BYTES = SCR_O + 4 * 6144; // 61440 = 60 KB -> 2 blocks/CU

__device__ __forceinline__ short f2bf(float f) {   // RNE float->bf16
    uint32_t u = __builtin_bit_cast(uint32_t, f);
    u += 0x7fffu + ((u >> 16) & 1u);
    return (short)(u >> 16);
}
__device__ __forceinline__ float fsig(float v) {
    return __builtin_amdgcn_rcpf(1.0f + __expf(-v));
}
__device__ __forceinline__ float ftanh(float v) {
    return 1.0f - 2.0f * __builtin_amdgcn_rcpf(1.0f + __expf(2.0f * v));
}

__global__ __launch_bounds__(256) void gclstm_mfma_kernel(
    const float* __restrict__ x,
    const float* __restrict__ W_i, const float* __restrict__ W_c, const float* __restrict__ W_o,
    const float* __restrict__ bc_i, const float* __restrict__ bc_c, const float* __restrict__ bc_o,
    const float* __restrict__ w_co,
    const float* __restrict__ b_i, const float* __restrict__ b_c, const float* __restrict__ b_o,
    const float* __restrict__ M1, const float* __restrict__ bm1,
    const float* __restrict__ M2, const float* __restrict__ bm2,
    const float* __restrict__ M3, const float* __restrict__ bm3,
    float* __restrict__ out, int n)
{
    __shared__ char lds[LDS_BYTES];
    const int tid  = threadIdx.x;
    const int wid  = tid >> 6;
    const int lane = tid & 63;
    const int g    = lane >> 4;     // lane group 0..3
    const int ln   = lane & 15;

    // ---------------- init: build bf16 fragment tables ----------------
    // Gate A-frags: A = W^T tile [16 hid x 32k(in, k>=16 dead)], lanes 0..31 real.
    if (lane < 32) {
        for (int t = wid; t < 24; t += 4) {
            const int gi = t >> 3, mt = t & 7;
            const float* Wg = (gi == 0) ? W_i : (gi == 1) ? W_c : W_o;
            const int row = mt * 16 + ln;     // hid index
            const int k0  = g * 8;            // input-feature index (g in 0..1)
            bf16x8 v;
            #pragma unroll
            for (int j = 0; j < 8; ++j) v[j] = f2bf(Wg[(k0 + j) * HID + row]);
            *(bf16x8*)(lds + GATE_F + t * 512 + lane * 16) = v;
        }
    }
    // M1^T frags: A[m][k] = M1[k*64+m]; m = m1-col, k = hid. 4 mt x 4 kt.
    for (int t = wid; t < 16; t += 4) {
        const int mt = t >> 2, kt = t & 3;
        const int row = mt * 16 + ln;
        const int k0  = kt * 32 + g * 8;
        bf16x8 v;
        #pragma unroll
        for (int j = 0; j < 8; ++j) v[j] = f2bf(M1[(k0 + j) * MH1 + row]);
        *(bf16x8*)(lds + M1_F + t * 1024 + lane * 16) = v;
    }
    // M2^T frags: A[m][k] = M2[k*32+m]. 2 mt x 2 kt.
    for (int t = wid; t < 4; t += 4) {
        const int mt = t >> 1, kt = t & 1;
        const int row = mt * 16 + ln;
        const int k0  = kt * 32 + g * 8;
        bf16x8 v;
        #pragma unroll
        for (int j = 0; j < 8; ++j) v[j] = f2bf(M2[(k0 + j) * MH2 + row]);
        *(bf16x8*)(lds + M2_F + t * 1024 + lane * 16) = v;
    }
    {
        float* biasS = (float*)(lds + BIAS_O);
        if (tid < HID) {
            biasS[tid]           = bc_i[tid] + b_i[tid];
            biasS[HID + tid]     = bc_c[tid] + b_c[tid];
            biasS[2 * HID + tid] = bc_o[tid] + b_o[tid];
            ((float*)(lds + WCO_O))[tid] = w_co[tid];
        }
        if (tid < MH1) ((float*)(lds + BM1_O))[tid] = bm1[tid];
        if (tid < MH2) { ((float*)(lds + M3_O))[tid] = M3[tid];
                         ((float*)(lds + BM2_O))[tid] = bm2[tid]; }
        if (tid == 0)  ((float*)(lds + BM3_O))[0] = bm3[0];
    }
    __syncthreads();

    char* HT  = lds + SCR_O + wid * 6144;   // H^T  B-frags: 4 kt x 1024
    char* M1T = HT + 4096;                  // m1^T B-frags: 2 kt x 1024
    const float* biasI = (const float*)(lds + BIAS_O);
    const float* biasC = biasI + HID;
    const float* biasO = biasC + HID;
    const float* wcoS  = (const float*)(lds + WCO_O);
    const float* m3S   = (const float*)(lds + M3_O);
    const float* bm1S  = (const float*)(lds + BM1_O);
    const float* bm2S  = (const float*)(lds + BM2_O);
    const float  bm3v  = ((const float*)(lds + BM3_O))[0];
    const f32x4 z = {0.f, 0.f, 0.f, 0.f};

    for (int it = 0; it < ITER; ++it) {
        const long tileIdx = (long)blockIdx.x * TILES_PER_BLOCK + it * 4 + wid;
        const long base = tileIdx * 16;
        if (base >= n) break;

        // x B-frag: lane holds col=node(ln), k=g*8+j; k>=16 -> 0.
        bf16x8 xf;
        #pragma unroll
        for (int j = 0; j < 8; ++j) xf[j] = 0;
        if (g < 2) {
            const float* xp = x + (base + ln) * IN_F + g * 8;
            float4 a = *(const float4*)xp;
            float4 b = *(const float4*)(xp + 4);
            xf[0] = f2bf(a.x); xf[1] = f2bf(a.y); xf[2] = f2bf(a.z); xf[3] = f2bf(a.w);
            xf[4] = f2bf(b.x); xf[5] = f2bf(b.y); xf[6] = f2bf(b.z); xf[7] = f2bf(b.w);
        }

        // ---- gates + activations, per 16-wide hid tile ----
        #pragma unroll
        for (int mt = 0; mt < 8; ++mt) {
            bf16x8 fi = *(const bf16x8*)(lds + GATE_F + (0 * 8 + mt) * 512 + (lane & 31) * 16);
            bf16x8 fc = *(const bf16x8*)(lds + GATE_F + (1 * 8 + mt) * 512 + (lane & 31) * 16);
            bf16x8 fo = *(const bf16x8*)(lds + GATE_F + (2 * 8 + mt) * 512 + (lane & 31) * 16);
            f32x4 ai = __builtin_amdgcn_mfma_f32_16x16x32_bf16(fi, xf, z, 0, 0, 0);
            f32x4 ac = __builtin_amdgcn_mfma_f32_16x16x32_bf16(fc, xf, z, 0, 0, 0);
            f32x4 ao = __builtin_amdgcn_mfma_f32_16x16x32_bf16(fo, xf, z, 0, 0, 0);

            const int h0 = mt * 16 + g * 4;             // hid index of acc[0]
            f32x4 bI = *(const f32x4*)(biasI + h0);
            f32x4 bC = *(const f32x4*)(biasC + h0);
            f32x4 bO = *(const f32x4*)(biasO + h0);
            f32x4 wc = *(const f32x4*)(wcoS + h0);
            float hv[4];
            #pragma unroll
            for (int i = 0; i < 4; ++i) {
                float I = fsig(ai[i] + bI[i]);
                float T = ftanh(ac[i] + bC[i]);
                float c = I * T;
                float O = fsig(fmaf(wc[i], c, ao[i] + bO[i]));
                hv[i] = fmaxf(O * ftanh(c), 0.f);       // relu(H)
            }
            uint32_t lo = (uint32_t)(uint16_t)f2bf(hv[0]) | ((uint32_t)(uint16_t)f2bf(hv[1]) << 16);
            uint32_t hi = (uint32_t)(uint16_t)f2bf(hv[2]) | ((uint32_t)(uint16_t)f2bf(hv[3]) << 16);
            // frag-linear H^T store: elem (hid q, node ln) at
            // (q>>5)*1024 + ((q&31)>>3)*256 + ln*16 + (q&7)*2 ; q = mt*16+g*4+i
            char* dst = HT + (mt >> 1) * 1024
                          + ((((mt & 1) * 2 + (g >> 1)) * 16 + ln) * 16)
                          + (g & 1) * 8;
            *(uint64_t*)dst = (uint64_t)lo | ((uint64_t)hi << 32);
        }

        // ---- MLP1: m1^T[64x16] = M1^T[64x128] @ H^T[128x16] ----
        bf16x8 hb0 = *(const bf16x8*)(HT + 0 * 1024 + lane * 16);
        bf16x8 hb1 = *(const bf16x8*)(HT + 1 * 1024 + lane * 16);
        bf16x8 hb2 = *(const bf16x8*)(HT + 2 * 1024 + lane * 16);
        bf16x8 hb3 = *(const bf16x8*)(HT + 3 * 1024 + lane * 16);
        #pragma unroll
        for (int mt = 0; mt < 4; ++mt) {
            f32x4 acc = z;
            acc = __builtin_amdgcn_mfma_f32_16x16x32_bf16(
                *(const bf16x8*)(lds + M1_F + (mt * 4 + 0) * 1024 + lane * 16), hb0, acc, 0, 0, 0);
            acc = __builtin_amdgcn_mfma_f32_16x16x32_bf16(
                *(const bf16x8*)(lds + M1_F + (mt * 4 + 1) * 1024 + lane * 16), hb1, acc, 0, 0, 0);
            acc = __builtin_amdgcn_mfma_f32_16x16x32_bf16(
                *(const bf16x8*)(lds + M1_F + (mt * 4 + 2) * 1024 + lane * 16), hb2, acc, 0, 0, 0);
            acc = __builtin_amdgcn_mfma_f32_16x16x32_bf16(
                *(const bf16x8*)(lds + M1_F + (mt * 4 + 3) * 1024 + lane * 16), hb3, acc, 0, 0, 0);
            const int r0 = mt * 16 + g * 4;             // m1 index
            f32x4 bb = *(const f32x4*)(bm1S + r0);
            float mv[4];
            #pragma unroll
            for (int i = 0; i < 4; ++i) mv[i] = fmaxf(acc[i] + bb[i], 0.f);
            uint32_t lo = (uint32_t)(uint16_t)f2bf(mv[0]) | ((uint32_t)(uint16_t)f2bf(mv[1]) << 16);
            uint32_t hi = (uint32_t)(uint16_t)f2bf(mv[2]) | ((uint32_t)(uint16_t)f2bf(mv[3]) << 16);
            char* dst = M1T + (mt >> 1) * 1024
                            + ((((mt & 1) * 2 + (g >> 1)) * 16 + ln) * 16)
                            + (g & 1) * 8;
            *(uint64_t*)dst = (uint64_t)lo | ((uint64_t)hi << 32);
        }

        // ---- MLP2 [32x64] + MLP3 dot, fused ----
        bf16x8 mb0 = *(const bf16x8*)(M1T + 0 * 1024 + lane * 16);
        bf16x8 mb1 = *(const bf16x8*)(M1T + 1 * 1024 + lane * 16);
        float outacc = 0.f;
        #pragma unroll
        for (int mt = 0; mt < 2; ++mt) {
            f32x4 acc = z;
            acc = __builtin_amdgcn_mfma_f32_16x16x32_bf16(
                *(const bf16x8*)(lds + M2_F + (mt * 2 + 0) * 1024 + lane * 16), mb0, acc, 0, 0, 0);
            acc = __builtin_amdgcn_mfma_f32_16x16x32_bf16(
                *(const bf16x8*)(lds + M2_F + (mt * 2 + 1) * 1024 + lane * 16), mb1, acc, 0, 0, 0);
            const int r0 = mt * 16 + g * 4;             // m2 index
            f32x4 b2 = *(const f32x4*)(bm2S + r0);
            f32x4 w3 = *(const f32x4*)(m3S + r0);
            #pragma unroll
            for (int i = 0; i < 4; ++i)
                outacc = fmaf(fmaxf(acc[i] + b2[i], 0.f), w3[i], outacc);
        }
        outacc += __shfl_xor(outacc, 16);
        outacc += __shfl_xor(outacc, 32);
        if (lane < 16) out[base + lane] = outacc + bm3v;
    }
}

extern "C" void kernel_launch(void* const* d_in, const int* in_sizes, int n_in,
                              void* d_out, int out_size, void* d_ws, size_t ws_size,
                              hipStream_t stream) {
    const float* x    = (const float*)d_in[0];
    // d_in[1] edge_index, d_in[2] edge_weight: dead (ChebConv K=1 on H=0)
    const float* W_i  = (const float*)d_in[3];
    // d_in[4] W_f: dead (multiplies C=0)
    const float* W_c  = (const float*)d_in[5];
    const float* W_o  = (const float*)d_in[6];
    // d_in[7..10] Uc_*: dead (H=0)
    const float* bc_i = (const float*)d_in[11];
    const float* bc_c = (const float*)d_in[13];
    const float* bc_o = (const float*)d_in[14];
    const float* w_co = (const float*)d_in[17];
    const float* b_i  = (const float*)d_in[18];
    const float* b_c  = (const float*)d_in[20];
    const float* b_o  = (const float*)d_in[21];
    const float* M1   = (const float*)d_in[22];
    const float* bm1  = (const float*)d_in[23];
    const float* M2   = (const float*)d_in[24];
    const float* bm2  = (const float*)d_in[25];
    const float* M3   = (const float*)d_in[26];
    const float* bm3  = (const float*)d_in[27];
    float* out = (float*)d_out;

    const int n = in_sizes[0] / IN_F;                   // 500000
    const int tiles = (n + 15) / 16;                    // 31250
    const int grid = (tiles + TILES_PER_BLOCK - 1) / TILES_PER_BLOCK;

    gclstm_mfma_kernel<<<grid, 256, 0, stream>>>(
        x, W_i, W_c, W_o, bc_i, bc_c, bc_o, w_co,
        b_i, b_c, b_o, M1, bm1, M2, bm2, M3, bm3, out, n);
}

// Round 3
// 86.282 us; speedup vs baseline: 5.8663x; 1.2150x over previous
//
#include <hip/hip_runtime.h>
#include <stdint.h>

// GCLSTM (single step, H=C=0) + MLP head, bf16 MFMA, fp32 accum/activations.
// Transposed formulation: G^T = W^T @ X^T, C-frags hold (col=node, row=feat).
// R3 changes vs R2:
//  - v_cvt_pk_bf16_f32 for all f32->bf16 pair packing (replaces ~14 ops with 1)
//  - biases fed as MFMA C-operand (broadcast f32x4 LDS read, no VALU adds)
//  - M1T scratch aliased onto HT (per-wave LDS ops are in-order => WAR safe):
//    LDS 60KB -> 51KB => 3 blocks/CU instead of 2.

typedef __attribute__((ext_vector_type(8))) short bf16x8;   // 8 bf16 = 4 VGPR
typedef __attribute__((ext_vector_type(4))) float f32x4;

constexpr int IN_F = 16;
constexpr int HID  = 128;
constexpr int MH1  = 64;
constexpr int MH2  = 32;
constexpr int ITER = 4;                     // tiles per wave per block
constexpr int TILES_PER_BLOCK = 4 * ITER;   // 4 waves

// ---- LDS byte offsets ----
constexpr int GATE_F = 0;                   // 24 tiles * 512 B (lanes 0..31 real)
constexpr int M1_F   = 12288;               // 16 tiles * 1024 B
constexpr int M2_F   = 28672;               // 4 tiles * 1024 B
constexpr int BIAS_O = 32768;               // 3*128 f32 (combined bc_*+b_*)
constexpr int WCO_O  = 34304;               // 128 f32
constexpr int M3_O   = 34816;               // 32 f32
constexpr int BM1_O  = 34944;               // 64 f32
constexpr int BM2_O  = 35200;               // 32 f32
constexpr int BM3_O  = 35328;               // 1 f32
constexpr int SCR_O  = 35840;               // per-wave scratch: 4096 (HT; M1T aliased)
constexpr int LDS_BYTES = SCR_O + 4 * 4096; // 52224 B -> 3 blocks/CU

__device__ __forceinline__ short f2bf(float f) {   // RNE float->bf16 (init only)
    uint32_t u = __builtin_bit_cast(uint32_t, f);
    u += 0x7fffu + ((u >> 16) & 1u);
    return (short)(u >> 16);
}
__device__ __forceinline__ uint32_t cvt_pk(float lo, float hi) {  // bf16(lo)|bf16(hi)<<16
    uint32_t r;
    asm("v_cvt_pk_bf16_f32 %0, %1, %2" : "=v"(r) : "v"(lo), "v"(hi));
    return r;
}
__device__ __forceinline__ float fsig(float v) {
    return __builtin_amdgcn_rcpf(1.0f + __expf(-v));
}
__device__ __forceinline__ float ftanh(float v) {
    return 1.0f - 2.0f * __builtin_amdgcn_rcpf(1.0f + __expf(2.0f * v));
}

__global__ __launch_bounds__(256) void gclstm_mfma_kernel(
    const float* __restrict__ x,
    const float* __restrict__ W_i, const float* __restrict__ W_c, const float* __restrict__ W_o,
    const float* __restrict__ bc_i, const float* __restrict__ bc_c, const float* __restrict__ bc_o,
    const float* __restrict__ w_co,
    const float* __restrict__ b_i, const float* __restrict__ b_c, const float* __restrict__ b_o,
    const float* __restrict__ M1, const float* __restrict__ bm1,
    const float* __restrict__ M2, const float* __restrict__ bm2,
    const float* __restrict__ M3, const float* __restrict__ bm3,
    float* __restrict__ out, int n)
{
    __shared__ char lds[LDS_BYTES];
    const int tid  = threadIdx.x;
    const int wid  = tid >> 6;
    const int lane = tid & 63;
    const int g    = lane >> 4;     // lane group 0..3
    const int ln   = lane & 15;

    // ---------------- init: build bf16 fragment tables ----------------
    if (lane < 32) {
        for (int t = wid; t < 24; t += 4) {
            const int gi = t >> 3, mt = t & 7;
            const float* Wg = (gi == 0) ? W_i : (gi == 1) ? W_c : W_o;
            const int row = mt * 16 + ln;     // hid index
            const int k0  = g * 8;            // input-feature index (g in 0..1)
            bf16x8 v;
            #pragma unroll
            for (int j = 0; j < 8; ++j) v[j] = f2bf(Wg[(k0 + j) * HID + row]);
            *(bf16x8*)(lds + GATE_F + t * 512 + lane * 16) = v;
        }
    }
    // M1^T frags: A[m][k] = M1[k*64+m]. 4 mt x 4 kt.
    for (int t = wid; t < 16; t += 4) {
        const int mt = t >> 2, kt = t & 3;
        const int row = mt * 16 + ln;
        const int k0  = kt * 32 + g * 8;
        bf16x8 v;
        #pragma unroll
        for (int j = 0; j < 8; ++j) v[j] = f2bf(M1[(k0 + j) * MH1 + row]);
        *(bf16x8*)(lds + M1_F + t * 1024 + lane * 16) = v;
    }
    // M2^T frags: A[m][k] = M2[k*32+m]. 2 mt x 2 kt.
    for (int t = wid; t < 4; t += 4) {
        const int mt = t >> 1, kt = t & 1;
        const int row = mt * 16 + ln;
        const int k0  = kt * 32 + g * 8;
        bf16x8 v;
        #pragma unroll
        for (int j = 0; j < 8; ++j) v[j] = f2bf(M2[(k0 + j) * MH2 + row]);
        *(bf16x8*)(lds + M2_F + t * 1024 + lane * 16) = v;
    }
    {
        float* biasS = (float*)(lds + BIAS_O);
        if (tid < HID) {
            biasS[tid]           = bc_i[tid] + b_i[tid];
            biasS[HID + tid]     = bc_c[tid] + b_c[tid];
            biasS[2 * HID + tid] = bc_o[tid] + b_o[tid];
            ((float*)(lds + WCO_O))[tid] = w_co[tid];
        }
        if (tid < MH1) ((float*)(lds + BM1_O))[tid] = bm1[tid];
        if (tid < MH2) { ((float*)(lds + M3_O))[tid]  = M3[tid];
                         ((float*)(lds + BM2_O))[tid] = bm2[tid]; }
        if (tid == 0)  ((float*)(lds + BM3_O))[0] = bm3[0];
    }
    __syncthreads();

    char* HT  = lds + SCR_O + wid * 4096;   // H^T B-frags: 4 kt x 1024
    char* M1T = HT;                          // aliased (in-order per-wave LDS)
    const float* biasI = (const float*)(lds + BIAS_O);
    const float* biasC = biasI + HID;
    const float* biasO = biasC + HID;
    const float* wcoS  = (const float*)(lds + WCO_O);
    const float* m3S   = (const float*)(lds + M3_O);
    const float* bm1S  = (const float*)(lds + BM1_O);
    const float* bm2S  = (const float*)(lds + BM2_O);
    const float  bm3v  = ((const float*)(lds + BM3_O))[0];
    const f32x4 z = {0.f, 0.f, 0.f, 0.f};

    for (int it = 0; it < ITER; ++it) {
        const long tileIdx = (long)blockIdx.x * TILES_PER_BLOCK + it * 4 + wid;
        const long base = tileIdx * 16;
        if (base >= n) break;

        // x B-frag: lane holds col=node(ln), k=g*8+j; k>=16 -> 0.
        bf16x8 xf;
        #pragma unroll
        for (int j = 0; j < 8; ++j) xf[j] = 0;
        if (g < 2) {
            const float* xp = x + (base + ln) * IN_F + g * 8;
            float4 a = *(const float4*)xp;
            float4 b = *(const float4*)(xp + 4);
            union { uint32_t u[4]; bf16x8 v; } cv;
            cv.u[0] = cvt_pk(a.x, a.y); cv.u[1] = cvt_pk(a.z, a.w);
            cv.u[2] = cvt_pk(b.x, b.y); cv.u[3] = cvt_pk(b.z, b.w);
            xf = cv.v;
        }

        // ---- gates + activations, per 16-wide hid tile ----
        #pragma unroll
        for (int mt = 0; mt < 8; ++mt) {
            const int h0 = mt * 16 + g * 4;             // hid index of acc[0]
            bf16x8 fi = *(const bf16x8*)(lds + GATE_F + (0 * 8 + mt) * 512 + (lane & 31) * 16);
            bf16x8 fc = *(const bf16x8*)(lds + GATE_F + (1 * 8 + mt) * 512 + (lane & 31) * 16);
            bf16x8 fo = *(const bf16x8*)(lds + GATE_F + (2 * 8 + mt) * 512 + (lane & 31) * 16);
            f32x4 bI = *(const f32x4*)(biasI + h0);
            f32x4 bC = *(const f32x4*)(biasC + h0);
            f32x4 bO = *(const f32x4*)(biasO + h0);
            f32x4 ai = __builtin_amdgcn_mfma_f32_16x16x32_bf16(fi, xf, bI, 0, 0, 0);
            f32x4 ac = __builtin_amdgcn_mfma_f32_16x16x32_bf16(fc, xf, bC, 0, 0, 0);
            f32x4 ao = __builtin_amdgcn_mfma_f32_16x16x32_bf16(fo, xf, bO, 0, 0, 0);

            f32x4 wc = *(const f32x4*)(wcoS + h0);
            float hv[4];
            #pragma unroll
            for (int i = 0; i < 4; ++i) {
                float I = fsig(ai[i]);
                float T = ftanh(ac[i]);
                float c = I * T;
                float O = fsig(fmaf(wc[i], c, ao[i]));
                hv[i] = fmaxf(O * ftanh(c), 0.f);       // relu(H)
            }
            // frag-linear H^T store: elem (hid q, node ln) at
            // (q>>5)*1024 + ((q&31)>>3)*256 + ln*16 + (q&7)*2 ; q = mt*16+g*4+i
            char* dst = HT + (mt >> 1) * 1024
                          + ((((mt & 1) * 2 + (g >> 1)) * 16 + ln) * 16)
                          + (g & 1) * 8;
            uint2 hp; hp.x = cvt_pk(hv[0], hv[1]); hp.y = cvt_pk(hv[2], hv[3]);
            *(uint2*)dst = hp;
        }

        // ---- MLP1: m1^T[64x16] = M1^T[64x128] @ H^T[128x16] ----
        bf16x8 hb0 = *(const bf16x8*)(HT + 0 * 1024 + lane * 16);
        bf16x8 hb1 = *(const bf16x8*)(HT + 1 * 1024 + lane * 16);
        bf16x8 hb2 = *(const bf16x8*)(HT + 2 * 1024 + lane * 16);
        bf16x8 hb3 = *(const bf16x8*)(HT + 3 * 1024 + lane * 16);
        #pragma unroll
        for (int mt = 0; mt < 4; ++mt) {
            const int r0 = mt * 16 + g * 4;             // m1 index
            f32x4 acc = *(const f32x4*)(bm1S + r0);     // bias as C-init
            acc = __builtin_amdgcn_mfma_f32_16x16x32_bf16(
                *(const bf16x8*)(lds + M1_F + (mt * 4 + 0) * 1024 + lane * 16), hb0, acc, 0, 0, 0);
            acc = __builtin_amdgcn_mfma_f32_16x16x32_bf16(
                *(const bf16x8*)(lds + M1_F + (mt * 4 + 1) * 1024 + lane * 16), hb1, acc, 0, 0, 0);
            acc = __builtin_amdgcn_mfma_f32_16x16x32_bf16(
                *(const bf16x8*)(lds + M1_F + (mt * 4 + 2) * 1024 + lane * 16), hb2, acc, 0, 0, 0);
            acc = __builtin_amdgcn_mfma_f32_16x16x32_bf16(
                *(const bf16x8*)(lds + M1_F + (mt * 4 + 3) * 1024 + lane * 16), hb3, acc, 0, 0, 0);
            float mv[4];
            #pragma unroll
            for (int i = 0; i < 4; ++i) mv[i] = fmaxf(acc[i], 0.f);
            char* dst = M1T + (mt >> 1) * 1024
                            + ((((mt & 1) * 2 + (g >> 1)) * 16 + ln) * 16)
                            + (g & 1) * 8;
            uint2 mp; mp.x = cvt_pk(mv[0], mv[1]); mp.y = cvt_pk(mv[2], mv[3]);
            *(uint2*)dst = mp;
        }

        // ---- MLP2 [32x64] + MLP3 dot, fused ----
        bf16x8 mb0 = *(const bf16x8*)(M1T + 0 * 1024 + lane * 16);
        bf16x8 mb1 = *(const bf16x8*)(M1T + 1 * 1024 + lane * 16);
        float outacc = 0.f;
        #pragma unroll
        for (int mt = 0; mt < 2; ++mt) {
            const int r0 = mt * 16 + g * 4;             // m2 index
            f32x4 acc = *(const f32x4*)(bm2S + r0);     // bias as C-init
            acc = __builtin_amdgcn_mfma_f32_16x16x32_bf16(
                *(const bf16x8*)(lds + M2_F + (mt * 2 + 0) * 1024 + lane * 16), mb0, acc, 0, 0, 0);
            acc = __builtin_amdgcn_mfma_f32_16x16x32_bf16(
                *(const bf16x8*)(lds + M2_F + (mt * 2 + 1) * 1024 + lane * 16), mb1, acc, 0, 0, 0);
            f32x4 w3 = *(const f32x4*)(m3S + r0);
            #pragma unroll
            for (int i = 0; i < 4; ++i)
                outacc = fmaf(fmaxf(acc[i], 0.f), w3[i], outacc);
        }
        outacc += __shfl_xor(outacc, 16);
        outacc += __shfl_xor(outacc, 32);
        if (lane < 16) out[base + lane] = outacc + bm3v;
    }
}

extern "C" void kernel_launch(void* const* d_in, const int* in_sizes, int n_in,
                              void* d_out, int out_size, void* d_ws, size_t ws_size,
                              hipStream_t stream) {
    const float* x    = (const float*)d_in[0];
    // d_in[1] edge_index, d_in[2] edge_weight: dead (ChebConv K=1 on H=0)
    const float* W_i  = (const float*)d_in[3];
    // d_in[4] W_f: dead (multiplies C=0)
    const float* W_c  = (const float*)d_in[5];
    const float* W_o  = (const float*)d_in[6];
    // d_in[7..10] Uc_*: dead (H=0)
    const float* bc_i = (const float*)d_in[11];
    const float* bc_c = (const float*)d_in[13];
    const float* bc_o = (const float*)d_in[14];
    const float* w_co = (const float*)d_in[17];
    const float* b_i  = (const float*)d_in[18];
    const float* b_c  = (const float*)d_in[20];
    const float* b_o  = (const float*)d_in[21];
    const float* M1   = (const float*)d_in[22];
    const float* bm1  = (const float*)d_in[23];
    const float* M2   = (const float*)d_in[24];
    const float* bm2  = (const float*)d_in[25];
    const float* M3   = (const float*)d_in[26];
    const float* bm3  = (const float*)d_in[27];
    float* out = (float*)d_out;

    const int n = in_sizes[0] / IN_F;                   // 500000
    const int tiles = (n + 15) / 16;                    // 31250
    const int grid = (tiles + TILES_PER_BLOCK - 1) / TILES_PER_BLOCK;

    gclstm_mfma_kernel<<<grid, 256, 0, stream>>>(
        x, W_i, W_c, W_o, bc_i, bc_c, bc_o, w_co,
        b_i, b_c, b_o, M1, bm1, M2, bm2, M3, bm3, out, n);
}

// Round 4
// 69.854 us; speedup vs baseline: 7.2460x; 1.2352x over previous
//
#include <hip/hip_runtime.h>
#include <stdint.h>

// GCLSTM (single step, H=C=0) + MLP head, bf16 MFMA, fp32 accum/activations.
// Transposed formulation: G^T = W^T @ X^T, C-frags hold (col=node, row=feat).
// R4 changes vs R3:
//  - log2e scales folded into weight/bias tables: raw v_exp_f32, no per-elem muls
//    (W_i,b_i *= -L; W_c,b_c *= 2L; W_o,b_o *= -L; w_co *= -1/2, applied to c'=2Lc)
//  - shared-rcp activation algebra: I*T=(Ec-1)/((1+Ei)(1+Ec)),
//    O*tanh(c)=(E2-1)/((1+Eo)(E2+1))  => 6 trans/elem instead of 8
//  - 512-thread blocks: 8 waves share one table copy; LDS 68.6KB -> 2 blocks/CU
//    = 16 waves/CU (was 12).

typedef __attribute__((ext_vector_type(8))) short bf16x8;   // 8 bf16 = 4 VGPR
typedef __attribute__((ext_vector_type(4))) float f32x4;

constexpr int IN_F = 16;
constexpr int HID  = 128;
constexpr int MH1  = 64;
constexpr int MH2  = 32;
constexpr int WAVES = 8;
constexpr int ITER  = 2;                        // tiles per wave per block
constexpr int TILES_PER_BLOCK = WAVES * ITER;   // 16

constexpr float LOG2E = 1.4426950408889634f;
constexpr float TWO_L = 2.8853900817779268f;

// ---- LDS byte offsets ----
constexpr int GATE_F = 0;                   // 24 tiles * 512 B (lanes 0..31 real)
constexpr int M1_F   = 12288;               // 16 tiles * 1024 B
constexpr int M2_F   = 28672;               // 4 tiles * 1024 B
constexpr int BIAS_O = 32768;               // 3*128 f32 (scaled bc_*+b_*)
constexpr int WCO_O  = 34304;               // 128 f32 (-w_co/2)
constexpr int M3_O   = 34816;               // 32 f32
constexpr int BM1_O  = 34944;               // 64 f32
constexpr int BM2_O  = 35200;               // 32 f32
constexpr int BM3_O  = 35328;               // 1 f32
constexpr int SCR_O  = 35840;               // per-wave scratch: 4096 (HT; M1T aliased)
constexpr int LDS_BYTES = SCR_O + WAVES * 4096;   // 68608 -> 2 blocks/CU

__device__ __forceinline__ short f2bf(float f) {   // RNE float->bf16 (init only)
    uint32_t u = __builtin_bit_cast(uint32_t, f);
    u += 0x7fffu + ((u >> 16) & 1u);
    return (short)(u >> 16);
}
__device__ __forceinline__ uint32_t cvt_pk(float lo, float hi) {  // bf16(lo)|bf16(hi)<<16
    uint32_t r;
    asm("v_cvt_pk_bf16_f32 %0, %1, %2" : "=v"(r) : "v"(lo), "v"(hi));
    return r;
}

__global__ __launch_bounds__(512) void gclstm_mfma_kernel(
    const float* __restrict__ x,
    const float* __restrict__ W_i, const float* __restrict__ W_c, const float* __restrict__ W_o,
    const float* __restrict__ bc_i, const float* __restrict__ bc_c, const float* __restrict__ bc_o,
    const float* __restrict__ w_co,
    const float* __restrict__ b_i, const float* __restrict__ b_c, const float* __restrict__ b_o,
    const float* __restrict__ M1, const float* __restrict__ bm1,
    const float* __restrict__ M2, const float* __restrict__ bm2,
    const float* __restrict__ M3, const float* __restrict__ bm3,
    float* __restrict__ out, int n)
{
    __shared__ char lds[LDS_BYTES];
    const int tid  = threadIdx.x;
    const int wid  = tid >> 6;
    const int lane = tid & 63;
    const int g    = lane >> 4;     // lane group 0..3
    const int ln   = lane & 15;

    // ---------------- init: build scaled bf16 fragment tables ----------------
    if (lane < 32) {
        for (int t = wid; t < 24; t += WAVES) {
            const int gi = t >> 3, mt = t & 7;
            const float* Wg = (gi == 0) ? W_i : (gi == 1) ? W_c : W_o;
            const float sc  = (gi == 1) ? TWO_L : -LOG2E;
            const int row = mt * 16 + ln;     // hid index
            const int k0  = g * 8;            // input-feature index (g in 0..1)
            bf16x8 v;
            #pragma unroll
            for (int j = 0; j < 8; ++j) v[j] = f2bf(Wg[(k0 + j) * HID + row] * sc);
            *(bf16x8*)(lds + GATE_F + t * 512 + lane * 16) = v;
        }
    }
    // M1^T frags: A[m][k] = M1[k*64+m]. 4 mt x 4 kt.
    for (int t = wid; t < 16; t += WAVES) {
        const int mt = t >> 2, kt = t & 3;
        const int row = mt * 16 + ln;
        const int k0  = kt * 32 + g * 8;
        bf16x8 v;
        #pragma unroll
        for (int j = 0; j < 8; ++j) v[j] = f2bf(M1[(k0 + j) * MH1 + row]);
        *(bf16x8*)(lds + M1_F + t * 1024 + lane * 16) = v;
    }
    // M2^T frags: A[m][k] = M2[k*32+m]. 2 mt x 2 kt.
    for (int t = wid; t < 4; t += WAVES) {
        const int mt = t >> 1, kt = t & 1;
        const int row = mt * 16 + ln;
        const int k0  = kt * 32 + g * 8;
        bf16x8 v;
        #pragma unroll
        for (int j = 0; j < 8; ++j) v[j] = f2bf(M2[(k0 + j) * MH2 + row]);
        *(bf16x8*)(lds + M2_F + t * 1024 + lane * 16) = v;
    }
    {
        float* biasS = (float*)(lds + BIAS_O);
        if (tid < HID) {
            biasS[tid]           = (bc_i[tid] + b_i[tid]) * (-LOG2E);
            biasS[HID + tid]     = (bc_c[tid] + b_c[tid]) * TWO_L;
            biasS[2 * HID + tid] = (bc_o[tid] + b_o[tid]) * (-LOG2E);
            ((float*)(lds + WCO_O))[tid] = -0.5f * w_co[tid];
        }
        if (tid < MH1) ((float*)(lds + BM1_O))[tid] = bm1[tid];
        if (tid < MH2) { ((float*)(lds + M3_O))[tid]  = M3[tid];
                         ((float*)(lds + BM2_O))[tid] = bm2[tid]; }
        if (tid == 0)  ((float*)(lds + BM3_O))[0] = bm3[0];
    }
    __syncthreads();

    char* HT  = lds + SCR_O + wid * 4096;   // H^T B-frags: 4 kt x 1024
    char* M1T = HT;                          // aliased (per-wave LDS ops in-order)
    const float* biasI = (const float*)(lds + BIAS_O);
    const float* biasC = biasI + HID;
    const float* biasO = biasC + HID;
    const float* wcoS  = (const float*)(lds + WCO_O);
    const float* m3S   = (const float*)(lds + M3_O);
    const float* bm1S  = (const float*)(lds + BM1_O);
    const float* bm2S  = (const float*)(lds + BM2_O);
    const float  bm3v  = ((const float*)(lds + BM3_O))[0];

    for (int it = 0; it < ITER; ++it) {
        const long tileIdx = (long)blockIdx.x * TILES_PER_BLOCK + it * WAVES + wid;
        const long base = tileIdx * 16;
        if (base >= n) break;

        // x B-frag: lane holds col=node(ln), k=g*8+j; k>=16 -> 0.
        bf16x8 xf;
        #pragma unroll
        for (int j = 0; j < 8; ++j) xf[j] = 0;
        if (g < 2) {
            const float* xp = x + (base + ln) * IN_F + g * 8;
            float4 a = *(const float4*)xp;
            float4 b = *(const float4*)(xp + 4);
            union { uint32_t u[4]; bf16x8 v; } cv;
            cv.u[0] = cvt_pk(a.x, a.y); cv.u[1] = cvt_pk(a.z, a.w);
            cv.u[2] = cvt_pk(b.x, b.y); cv.u[3] = cvt_pk(b.z, b.w);
            xf = cv.v;
        }

        // ---- gates + activations, per 16-wide hid tile ----
        #pragma unroll
        for (int mt = 0; mt < 8; ++mt) {
            const int h0 = mt * 16 + g * 4;             // hid index of acc[0]
            bf16x8 fi = *(const bf16x8*)(lds + GATE_F + (0 * 8 + mt) * 512 + (lane & 31) * 16);
            bf16x8 fc = *(const bf16x8*)(lds + GATE_F + (1 * 8 + mt) * 512 + (lane & 31) * 16);
            bf16x8 fo = *(const bf16x8*)(lds + GATE_F + (2 * 8 + mt) * 512 + (lane & 31) * 16);
            f32x4 bI = *(const f32x4*)(biasI + h0);
            f32x4 bC = *(const f32x4*)(biasC + h0);
            f32x4 bO = *(const f32x4*)(biasO + h0);
            // ai = -L*a_i ; ac = 2L*a_c ; ao = -L*(x@W_o+b_o)
            f32x4 ai = __builtin_amdgcn_mfma_f32_16x16x32_bf16(fi, xf, bI, 0, 0, 0);
            f32x4 ac = __builtin_amdgcn_mfma_f32_16x16x32_bf16(fc, xf, bC, 0, 0, 0);
            f32x4 ao = __builtin_amdgcn_mfma_f32_16x16x32_bf16(fo, xf, bO, 0, 0, 0);

            f32x4 wc = *(const f32x4*)(wcoS + h0);      // -w_co/2
            float hv[4];
            #pragma unroll
            for (int i = 0; i < 4; ++i) {
                float Ei = __builtin_amdgcn_exp2f(ai[i]);               // e^{-a_i}
                float Ec = __builtin_amdgcn_exp2f(ac[i]);               // e^{2 a_c}
                float R1 = __builtin_amdgcn_rcpf((1.0f + Ei) * (1.0f + Ec));
                float cp = (Ec - 1.0f) * R1 * TWO_L;                    // 2L*c
                float Eo = __builtin_amdgcn_exp2f(fmaf(wc[i], cp, ao[i])); // e^{-a_o}
                float E2 = __builtin_amdgcn_exp2f(cp);                  // e^{2c}
                float R2 = __builtin_amdgcn_rcpf((1.0f + Eo) * (E2 + 1.0f));
                hv[i] = fmaxf((E2 - 1.0f) * R2, 0.0f);                  // relu(O*tanh(c))
            }
            // frag-linear H^T store: elem (hid q, node ln), q = mt*16+g*4+i
            char* dst = HT + (mt >> 1) * 1024
                          + ((((mt & 1) * 2 + (g >> 1)) * 16 + ln) * 16)
                          + (g & 1) * 8;
            uint2 hp; hp.x = cvt_pk(hv[0], hv[1]); hp.y = cvt_pk(hv[2], hv[3]);
            *(uint2*)dst = hp;
        }

        // ---- MLP1: m1^T[64x16] = M1^T[64x128] @ H^T[128x16] ----
        bf16x8 hb0 = *(const bf16x8*)(HT + 0 * 1024 + lane * 16);
        bf16x8 hb1 = *(const bf16x8*)(HT + 1 * 1024 + lane * 16);
        bf16x8 hb2 = *(const bf16x8*)(HT + 2 * 1024 + lane * 16);
        bf16x8 hb3 = *(const bf16x8*)(HT + 3 * 1024 + lane * 16);
        #pragma unroll
        for (int mt = 0; mt < 4; ++mt) {
            const int r0 = mt * 16 + g * 4;             // m1 index
            f32x4 acc = *(const f32x4*)(bm1S + r0);     // bias as C-init
            acc = __builtin_amdgcn_mfma_f32_16x16x32_bf16(
                *(const bf16x8*)(lds + M1_F + (mt * 4 + 0) * 1024 + lane * 16), hb0, acc, 0, 0, 0);
            acc = __builtin_amdgcn_mfma_f32_16x16x32_bf16(
                *(const bf16x8*)(lds + M1_F + (mt * 4 + 1) * 1024 + lane * 16), hb1, acc, 0, 0, 0);
            acc = __builtin_amdgcn_mfma_f32_16x16x32_bf16(
                *(const bf16x8*)(lds + M1_F + (mt * 4 + 2) * 1024 + lane * 16), hb2, acc, 0, 0, 0);
            acc = __builtin_amdgcn_mfma_f32_16x16x32_bf16(
                *(const bf16x8*)(lds + M1_F + (mt * 4 + 3) * 1024 + lane * 16), hb3, acc, 0, 0, 0);
            float mv[4];
            #pragma unroll
            for (int i = 0; i < 4; ++i) mv[i] = fmaxf(acc[i], 0.f);
            char* dst = M1T + (mt >> 1) * 1024
                            + ((((mt & 1) * 2 + (g >> 1)) * 16 + ln) * 16)
                            + (g & 1) * 8;
            uint2 mp; mp.x = cvt_pk(mv[0], mv[1]); mp.y = cvt_pk(mv[2], mv[3]);
            *(uint2*)dst = mp;
        }

        // ---- MLP2 [32x64] + MLP3 dot, fused ----
        bf16x8 mb0 = *(const bf16x8*)(M1T + 0 * 1024 + lane * 16);
        bf16x8 mb1 = *(const bf16x8*)(M1T + 1 * 1024 + lane * 16);
        float outacc = 0.f;
        #pragma unroll
        for (int mt = 0; mt < 2; ++mt) {
            const int r0 = mt * 16 + g * 4;             // m2 index
            f32x4 acc = *(const f32x4*)(bm2S + r0);     // bias as C-init
            acc = __builtin_amdgcn_mfma_f32_16x16x32_bf16(
                *(const bf16x8*)(lds + M2_F + (mt * 2 + 0) * 1024 + lane * 16), mb0, acc, 0, 0, 0);
            acc = __builtin_amdgcn_mfma_f32_16x16x32_bf16(
                *(const bf16x8*)(lds + M2_F + (mt * 2 + 1) * 1024 + lane * 16), mb1, acc, 0, 0, 0);
            f32x4 w3 = *(const f32x4*)(m3S + r0);
            #pragma unroll
            for (int i = 0; i < 4; ++i)
                outacc = fmaf(fmaxf(acc[i], 0.f), w3[i], outacc);
        }
        outacc += __shfl_xor(outacc, 16);
        outacc += __shfl_xor(outacc, 32);
        if (lane < 16) out[base + lane] = outacc + bm3v;
    }
}

extern "C" void kernel_launch(void* const* d_in, const int* in_sizes, int n_in,
                              void* d_out, int out_size, void* d_ws, size_t ws_size,
                              hipStream_t stream) {
    const float* x    = (const float*)d_in[0];
    // d_in[1] edge_index, d_in[2] edge_weight: dead (ChebConv K=1 on H=0)
    const float* W_i  = (const float*)d_in[3];
    // d_in[4] W_f: dead (multiplies C=0)
    const float* W_c  = (const float*)d_in[5];
    const float* W_o  = (const float*)d_in[6];
    // d_in[7..10] Uc_*: dead (H=0)
    const float* bc_i = (const float*)d_in[11];
    const float* bc_c = (const float*)d_in[13];
    const float* bc_o = (const float*)d_in[14];
    const float* w_co = (const float*)d_in[17];
    const float* b_i  = (const float*)d_in[18];
    const float* b_c  = (const float*)d_in[20];
    const float* b_o  = (const float*)d_in[21];
    const float* M1   = (const float*)d_in[22];
    const float* bm1  = (const float*)d_in[23];
    const float* M2   = (const float*)d_in[24];
    const float* bm2  = (const float*)d_in[25];
    const float* M3   = (const float*)d_in[26];
    const float* bm3  = (const float*)d_in[27];
    float* out = (float*)d_out;

    const int n = in_sizes[0] / IN_F;                   // 500000
    const int tiles = (n + 15) / 16;                    // 31250
    const int grid = (tiles + TILES_PER_BLOCK - 1) / TILES_PER_BLOCK;

    gclstm_mfma_kernel<<<grid, 512, 0, stream>>>(
        x, W_i, W_c, W_o, bc_i, bc_c, bc_o, w_co,
        b_i, b_c, b_o, M1, bm1, M2, bm2, M3, bm3, out, n);
}

// Round 5
// 62.073 us; speedup vs baseline: 8.1542x; 1.1253x over previous
//
#include <hip/hip_runtime.h>
#include <stdint.h>

// GCLSTM (single step, H=C=0) + MLP head, bf16 MFMA, fp32 accum/activations.
// Transposed formulation: G^T = W^T @ X^T, C-frags hold (col=node, row=feat).
// R5 changes vs R4:
//  - Permuted weight-row assignment hid(mt,r) = (mt>>1)*32+(r>>2)*8+(mt&1)*4+(r&3)
//    makes each lane's gate C-frag values exactly its MLP1 B-frag values:
//    B-frag(kt) = hpk[4kt..4kt+3] (register aliasing). Same for M1 rows -> MLP2.
//    => H^T/M1T LDS round-trip eliminated (no scratch, no ds_write/read, no sync).
//  - LDS 68.6KB -> 34.6KB => 4 blocks/CU; __launch_bounds__(512,8) for 32 waves/CU.

typedef __attribute__((ext_vector_type(8))) short bf16x8;   // 8 bf16 = 4 VGPR
typedef __attribute__((ext_vector_type(4))) float f32x4;

constexpr int IN_F = 16;
constexpr int HID  = 128;
constexpr int MH1  = 64;
constexpr int MH2  = 32;
constexpr int WAVES = 8;
constexpr int ITER  = 2;                        // tiles per wave per block
constexpr int TILES_PER_BLOCK = WAVES * ITER;   // 16

constexpr float LOG2E = 1.4426950408889634f;
constexpr float TWO_L = 2.8853900817779268f;

// ---- LDS byte offsets ----
constexpr int GATE_F = 0;                   // 24 tiles * 512 B (lanes 0..31 real)
constexpr int M1_F   = 12288;               // 16 tiles * 1024 B
constexpr int M2_F   = 28672;               // 4 tiles * 1024 B
constexpr int BIAS_O = 32768;               // 3*128 f32 (scaled, hid-permuted)
constexpr int WCO_O  = 34304;               // 128 f32 (-w_co/2, hid-permuted)
constexpr int M3_O   = 34816;               // 32 f32
constexpr int BM1_O  = 34944;               // 64 f32 (m1-permuted)
constexpr int BM2_O  = 35200;               // 32 f32
constexpr int BM3_O  = 35328;               // 1 f32
constexpr int LDS_BYTES = 35392;            // -> 4 blocks/CU

__device__ __forceinline__ short f2bf(float f) {   // RNE float->bf16 (init only)
    uint32_t u = __builtin_bit_cast(uint32_t, f);
    u += 0x7fffu + ((u >> 16) & 1u);
    return (short)(u >> 16);
}
__device__ __forceinline__ uint32_t cvt_pk(float lo, float hi) {  // bf16(lo)|bf16(hi)<<16
    uint32_t r;
    asm("v_cvt_pk_bf16_f32 %0, %1, %2" : "=v"(r) : "v"(lo), "v"(hi));
    return r;
}
// row permutation: tile mt (0..T-1), row r (0..15) -> feature index
__device__ __forceinline__ int permrow(int mt, int r) {
    return ((mt >> 1) << 5) + ((r >> 2) << 3) + ((mt & 1) << 2) + (r & 3);
}

__global__ __launch_bounds__(512, 8) void gclstm_mfma_kernel(
    const float* __restrict__ x,
    const float* __restrict__ W_i, const float* __restrict__ W_c, const float* __restrict__ W_o,
    const float* __restrict__ bc_i, const float* __restrict__ bc_c, const float* __restrict__ bc_o,
    const float* __restrict__ w_co,
    const float* __restrict__ b_i, const float* __restrict__ b_c, const float* __restrict__ b_o,
    const float* __restrict__ M1, const float* __restrict__ bm1,
    const float* __restrict__ M2, const float* __restrict__ bm2,
    const float* __restrict__ M3, const float* __restrict__ bm3,
    float* __restrict__ out, int n)
{
    __shared__ __align__(16) char lds[LDS_BYTES];
    const int tid  = threadIdx.x;
    const int wid  = tid >> 6;
    const int lane = tid & 63;
    const int g    = lane >> 4;     // lane group 0..3
    const int ln   = lane & 15;

    // ---------------- init: build scaled, row-permuted bf16 fragment tables ----
    if (lane < 32) {
        for (int t = wid; t < 24; t += WAVES) {
            const int gi = t >> 3, mt = t & 7;
            const float* Wg = (gi == 0) ? W_i : (gi == 1) ? W_c : W_o;
            const float sc  = (gi == 1) ? TWO_L : -LOG2E;
            const int row = permrow(mt, ln);  // permuted hid index
            const int k0  = g * 8;            // input-feature index (g in 0..1)
            bf16x8 v;
            #pragma unroll
            for (int j = 0; j < 8; ++j) v[j] = f2bf(Wg[(k0 + j) * HID + row] * sc);
            *(bf16x8*)(lds + GATE_F + t * 512 + lane * 16) = v;
        }
    }
    // M1^T frags: A[r][k] = M1[k*64 + permrow(mt1, r)]; K(hid) natural order.
    for (int t = wid; t < 16; t += WAVES) {
        const int mt = t >> 2, kt = t & 3;
        const int row = permrow(mt, ln);      // permuted m1 index (mt in 0..3)
        const int k0  = kt * 32 + g * 8;
        bf16x8 v;
        #pragma unroll
        for (int j = 0; j < 8; ++j) v[j] = f2bf(M1[(k0 + j) * MH1 + row]);
        *(bf16x8*)(lds + M1_F + t * 1024 + lane * 16) = v;
    }
    // M2^T frags: A[r][k] = M2[k*32 + (mt2*16+r)]; K(m1) natural; rows natural.
    for (int t = wid; t < 4; t += WAVES) {
        const int mt = t >> 1, kt = t & 1;
        const int row = mt * 16 + ln;
        const int k0  = kt * 32 + g * 8;
        bf16x8 v;
        #pragma unroll
        for (int j = 0; j < 8; ++j) v[j] = f2bf(M2[(k0 + j) * MH2 + row]);
        *(bf16x8*)(lds + M2_F + t * 1024 + lane * 16) = v;
    }
    {
        float* biasS = (float*)(lds + BIAS_O);
        if (tid < HID) {
            const int h = permrow(tid >> 4, tid & 15);    // hid perm, mt in 0..7
            biasS[tid]           = (bc_i[h] + b_i[h]) * (-LOG2E);
            biasS[HID + tid]     = (bc_c[h] + b_c[h]) * TWO_L;
            biasS[2 * HID + tid] = (bc_o[h] + b_o[h]) * (-LOG2E);
            ((float*)(lds + WCO_O))[tid] = -0.5f * w_co[h];
        }
        if (tid < MH1) {
            const int m = permrow(tid >> 4, tid & 15);    // m1 perm, mt in 0..3
            ((float*)(lds + BM1_O))[tid] = bm1[m];
        }
        if (tid < MH2) { ((float*)(lds + M3_O))[tid]  = M3[tid];
                         ((float*)(lds + BM2_O))[tid] = bm2[tid]; }
        if (tid == 0)  ((float*)(lds + BM3_O))[0] = bm3[0];
    }
    __syncthreads();

    const float* biasI = (const float*)(lds + BIAS_O);
    const float* biasC = biasI + HID;
    const float* biasO = biasC + HID;
    const float* wcoS  = (const float*)(lds + WCO_O);
    const float* m3S   = (const float*)(lds + M3_O);
    const float* bm1S  = (const float*)(lds + BM1_O);
    const float* bm2S  = (const float*)(lds + BM2_O);
    const float  bm3v  = ((const float*)(lds + BM3_O))[0];

    for (int it = 0; it < ITER; ++it) {
        const long tileIdx = (long)blockIdx.x * TILES_PER_BLOCK + it * WAVES + wid;
        const long base = tileIdx * 16;
        if (base >= n) break;

        // x B-frag: lane holds col=node(ln), k=g*8+j; k>=16 -> 0.
        bf16x8 xf;
        #pragma unroll
        for (int j = 0; j < 8; ++j) xf[j] = 0;
        if (g < 2) {
            const float* xp = x + (base + ln) * IN_F + g * 8;
            float4 a = *(const float4*)xp;
            float4 b = *(const float4*)(xp + 4);
            union { uint32_t u[4]; bf16x8 v; } cv;
            cv.u[0] = cvt_pk(a.x, a.y); cv.u[1] = cvt_pk(a.z, a.w);
            cv.u[2] = cvt_pk(b.x, b.y); cv.u[3] = cvt_pk(b.z, b.w);
            xf = cv.v;
        }

        // ---- gates + activations; hpk[2mt..2mt+1] = packed H for permuted rows.
        // Lane ends up holding H[hid = kt*32 + g*8 + j] in hpk[4kt + (j>>1)] halves.
        uint32_t hpk[16];
        #pragma unroll
        for (int mt = 0; mt < 8; ++mt) {
            const int h0 = mt * 16 + g * 4;             // permuted-bias position
            bf16x8 fi = *(const bf16x8*)(lds + GATE_F + (0 * 8 + mt) * 512 + (lane & 31) * 16);
            bf16x8 fc = *(const bf16x8*)(lds + GATE_F + (1 * 8 + mt) * 512 + (lane & 31) * 16);
            bf16x8 fo = *(const bf16x8*)(lds + GATE_F + (2 * 8 + mt) * 512 + (lane & 31) * 16);
            f32x4 bI = *(const f32x4*)(biasI + h0);
            f32x4 bC = *(const f32x4*)(biasC + h0);
            f32x4 bO = *(const f32x4*)(biasO + h0);
            // ai = -L*a_i ; ac = 2L*a_c ; ao = -L*(x@W_o+b_o)
            f32x4 ai = __builtin_amdgcn_mfma_f32_16x16x32_bf16(fi, xf, bI, 0, 0, 0);
            f32x4 ac = __builtin_amdgcn_mfma_f32_16x16x32_bf16(fc, xf, bC, 0, 0, 0);
            f32x4 ao = __builtin_amdgcn_mfma_f32_16x16x32_bf16(fo, xf, bO, 0, 0, 0);

            f32x4 wc = *(const f32x4*)(wcoS + h0);      // -w_co/2
            float hv[4];
            #pragma unroll
            for (int i = 0; i < 4; ++i) {
                float Ei = __builtin_amdgcn_exp2f(ai[i]);                  // e^{-a_i}
                float Ec = __builtin_amdgcn_exp2f(ac[i]);                  // e^{2 a_c}
                float R1 = __builtin_amdgcn_rcpf((1.0f + Ei) * (1.0f + Ec));
                float cp = (Ec - 1.0f) * R1 * TWO_L;                       // 2L*c
                float Eo = __builtin_amdgcn_exp2f(fmaf(wc[i], cp, ao[i])); // e^{-a_o}
                float E2 = __builtin_amdgcn_exp2f(cp);                     // e^{2c}
                float R2 = __builtin_amdgcn_rcpf((1.0f + Eo) * (E2 + 1.0f));
                hv[i] = fmaxf((E2 - 1.0f) * R2, 0.0f);                     // relu(O*tanh(c))
            }
            hpk[mt * 2]     = cvt_pk(hv[0], hv[1]);
            hpk[mt * 2 + 1] = cvt_pk(hv[2], hv[3]);
        }

        // ---- MLP1: m1^T = M1^T @ H^T ; B-frag(kt) = hpk[4kt..4kt+3] ----
        uint32_t mpk[8];
        #pragma unroll
        for (int mt = 0; mt < 4; ++mt) {
            const int r0 = mt * 16 + g * 4;             // permuted-bias position
            f32x4 acc = *(const f32x4*)(bm1S + r0);     // bias as C-init
            #pragma unroll
            for (int kt = 0; kt < 4; ++kt) {
                union { uint32_t u[4]; bf16x8 v; } b;
                b.u[0] = hpk[4 * kt + 0]; b.u[1] = hpk[4 * kt + 1];
                b.u[2] = hpk[4 * kt + 2]; b.u[3] = hpk[4 * kt + 3];
                acc = __builtin_amdgcn_mfma_f32_16x16x32_bf16(
                    *(const bf16x8*)(lds + M1_F + (mt * 4 + kt) * 1024 + lane * 16), b.v, acc, 0, 0, 0);
            }
            float mv[4];
            #pragma unroll
            for (int i = 0; i < 4; ++i) mv[i] = fmaxf(acc[i], 0.f);
            mpk[mt * 2]     = cvt_pk(mv[0], mv[1]);
            mpk[mt * 2 + 1] = cvt_pk(mv[2], mv[3]);
        }

        // ---- MLP2 [32x64] + MLP3 dot; B-frag(kt2) = mpk[4kt2..4kt2+3] ----
        float outacc = 0.f;
        #pragma unroll
        for (int mt = 0; mt < 2; ++mt) {
            const int r0 = mt * 16 + g * 4;             // m2 index (natural)
            f32x4 acc = *(const f32x4*)(bm2S + r0);     // bias as C-init
            #pragma unroll
            for (int kt = 0; kt < 2; ++kt) {
                union { uint32_t u[4]; bf16x8 v; } b;
                b.u[0] = mpk[4 * kt + 0]; b.u[1] = mpk[4 * kt + 1];
                b.u[2] = mpk[4 * kt + 2]; b.u[3] = mpk[4 * kt + 3];
                acc = __builtin_amdgcn_mfma_f32_16x16x32_bf16(
                    *(const bf16x8*)(lds + M2_F + (mt * 2 + kt) * 1024 + lane * 16), b.v, acc, 0, 0, 0);
            }
            f32x4 w3 = *(const f32x4*)(m3S + r0);
            #pragma unroll
            for (int i = 0; i < 4; ++i)
                outacc = fmaf(fmaxf(acc[i], 0.f), w3[i], outacc);
        }
        outacc += __shfl_xor(outacc, 16);
        outacc += __shfl_xor(outacc, 32);
        if (lane < 16) out[base + lane] = outacc + bm3v;
    }
}

extern "C" void kernel_launch(void* const* d_in, const int* in_sizes, int n_in,
                              void* d_out, int out_size, void* d_ws, size_t ws_size,
                              hipStream_t stream) {
    const float* x    = (const float*)d_in[0];
    // d_in[1] edge_index, d_in[2] edge_weight: dead (ChebConv K=1 on H=0)
    const float* W_i  = (const float*)d_in[3];
    // d_in[4] W_f: dead (multiplies C=0)
    const float* W_c  = (const float*)d_in[5];
    const float* W_o  = (const float*)d_in[6];
    // d_in[7..10] Uc_*: dead (H=0)
    const float* bc_i = (const float*)d_in[11];
    const float* bc_c = (const float*)d_in[13];
    const float* bc_o = (const float*)d_in[14];
    const float* w_co = (const float*)d_in[17];
    const float* b_i  = (const float*)d_in[18];
    const float* b_c  = (const float*)d_in[20];
    const float* b_o  = (const float*)d_in[21];
    const float* M1   = (const float*)d_in[22];
    const float* bm1  = (const float*)d_in[23];
    const float* M2   = (const float*)d_in[24];
    const float* bm2  = (const float*)d_in[25];
    const float* M3   = (const float*)d_in[26];
    const float* bm3  = (const float*)d_in[27];
    float* out = (float*)d_out;

    const int n = in_sizes[0] / IN_F;                   // 500000
    const int tiles = (n + 15) / 16;                    // 31250
    const int grid = (tiles + TILES_PER_BLOCK - 1) / TILES_PER_BLOCK;

    gclstm_mfma_kernel<<<grid, 512, 0, stream>>>(
        x, W_i, W_c, W_o, bc_i, bc_c, bc_o, w_co,
        b_i, b_c, b_o, M1, bm1, M2, bm2, M3, bm3, out, n);
}